// Round 9
// baseline (166.582 us; speedup 1.0000x reference)
//
#include <hip/hip_runtime.h>
#include <hip/hip_bf16.h>

// Problem constants
#define BPn   2048      // B*P
#define NEn   400
#define BT    2         // bp rows per tile
#define ET    8         // e rows per tile  -> 16-row wave tiles
#define NT    51200     // (2048/2)*(400/8)
#define GRID  512       // 2 blocks/CU; 4 waves/block -> 2048 waves; NT/2048 = 25 exactly

typedef __attribute__((ext_vector_type(8)))  short  short8;
typedef __attribute__((ext_vector_type(4)))  short  short4v;
typedef __attribute__((ext_vector_type(4)))  float  f32x4v;

__device__ __forceinline__ unsigned short bf16c(float x) {
  return __builtin_bit_cast(unsigned short, __float2bfloat16(x));
}

// ---------------- prep: hp/ehp[2048][128] and he/ehe[400][128] (f32) ----------------
__global__ void prep_emb(const int* __restrict__ z_j, const int* __restrict__ z_k,
                         const float* __restrict__ e_feat, const float* __restrict__ z_emb,
                         const float* __restrict__ W1, const float* __restrict__ b1,
                         float* __restrict__ hp, float* __restrict__ he,
                         float* __restrict__ ehp, float* __restrict__ ehe)
{
  const int t = threadIdx.x;           // 0..127
  const int bidx = blockIdx.x;
  if (bidx < BPn) {
    const int zj = z_j[bidx], zk = z_k[bidx];
    const float* ej = z_emb + zj * 64;
    const float* ek = z_emb + zk * 64;
    float acc = b1[t];
    #pragma unroll 8
    for (int k = 0; k < 64; ++k) acc += ej[k] * W1[k * 128 + t];
    #pragma unroll 8
    for (int k = 0; k < 64; ++k) acc += ek[k] * W1[(64 + k) * 128 + t];
    hp[bidx * 128 + t]  = acc;
    ehp[bidx * 128 + t] = __expf(-acc);
  } else {
    const int e = bidx - BPn;          // 0..399
    float acc = 0.0f;
    #pragma unroll 8
    for (int k = 0; k < 32; ++k) acc += e_feat[e * 32 + k] * W1[(128 + k) * 128 + t];
    he[e * 128 + t]  = acc;
    ehe[e * 128 + t] = __expf(-acc);
  }
}

// ---------------- prep: weights to bf16 fragments ----------------
// w2f: A-slot fragments of 16x16x32 mfma (GEMM1, swapped):
//   idx = ((g*4+ks)*64 + l)*8 + j  ->  bf16(W2[ks*32+(l>>4)*8+j][g*16+(l&15)])
// w3f: B-slot fragments (GEMM2): [ks][l][j] -> bf16(W3[ks*32+((l>>4)&3)*8+j][l&15])
__global__ void prep_w(const float* __restrict__ W2, const float* __restrict__ W3,
                       unsigned short* __restrict__ w2f, unsigned short* __restrict__ w3f)
{
  const int idx = blockIdx.x * 256 + threadIdx.x;
  if (idx < 16384) {
    const int j  = idx & 7;
    const int l  = (idx >> 3) & 63;
    const int ks = (idx >> 9) & 3;
    const int g  = idx >> 11;
    const int k  = ks * 32 + (l >> 4) * 8 + j;
    const int col = g * 16 + (l & 15);
    w2f[idx] = bf16c(W2[k * 128 + col]);
  }
  if (idx < 2048) {
    const int ks = idx >> 9;
    const int l  = (idx >> 3) & 63;
    const int j  = idx & 7;
    const int k  = ks * 32 + ((l >> 4) & 3) * 8 + j;
    const int col = l & 15;
    w3f[idx] = bf16c(W3[k * 16 + col]);
  }
}

// ---------------- fused main: wave-autonomous, zero in-loop barriers ----------------
// Each wave: 16-row tile (2bp x 8e) x 128. W2 entirely in registers (128 VGPRs).
// BUILD is fused into GEMM1 (A never materialized). H2 goes through a wave-private
// XOR-swizzled LDS slab (intra-wave lgkmcnt ordering only -> no __syncthreads).
__global__ __launch_bounds__(256, 2)
void fused_main(const float* __restrict__ hp, const float* __restrict__ he,
                const float* __restrict__ ehp, const float* __restrict__ ehe,
                const unsigned short* __restrict__ w2f, const unsigned short* __restrict__ w3f,
                const float* __restrict__ b2, const float* __restrict__ b3,
                float* __restrict__ out)
{
  __shared__ __align__(16) unsigned short ldsH[8192]; // 4 waves x 4KB private H2 slabs
  __shared__ __align__(16) float          ldsB2[128]; // b2 (broadcast reads)
  const int t    = threadIdx.x;
  const int lane = t & 63;
  const int wid  = t >> 6;
  const int r    = lane & 15;        // our tile row (both GEMM1 B-slot and GEMM2 A-slot)
  const int o    = lane >> 4;        // k-octet / col-quad selector
  const int rx   = (r & 7) << 4;     // LDS XOR swizzle for this lane's row

  // ---- W2 fragments: 8 col-groups x 4 k-steps, 4 VGPRs each = 128 VGPRs ----
  short8 w2r[8][4];
  #pragma unroll
  for (int g = 0; g < 8; ++g)
    #pragma unroll
    for (int ks = 0; ks < 4; ++ks)
      w2r[g][ks] = *(const short8*)(w2f + ((g * 4 + ks) * 64 + lane) * 8);

  if (t < 128) ldsB2[t] = b2[t];
  __syncthreads();                   // the only barrier (b2 staging)

  const float b3v = b3[r];
  char* slab = (char*)ldsH + wid * 4096;

  const int gwid = blockIdx.x * 4 + wid;
  for (int tile = gwid; tile < NT; tile += 2048) {
    const int tbp = (int)(((unsigned long long)(unsigned)tile * 2748779070ull) >> 37); // tile/50
    const int te  = tile - tbp * 50;
    const int b0  = tbp * BT;
    const int e0  = te * ET;

    const float* hpb = hp  + (b0 + (r >> 3)) * 128;
    const float* epb = ehp + (b0 + (r >> 3)) * 128;
    const float* heb = he  + (e0 + (r & 7)) * 128;
    const float* egb = ehe + (e0 + (r & 7)) * 128;

    // ---- GEMM1 with fused BUILD: acc[g][q] = H2pre[r][g*16 + o*4 + q] ----
    f32x4v acc[8] = {};
    #pragma unroll
    for (int ks = 0; ks < 4; ++ks) {
      const int k0 = ks * 32 + o * 8;
      const f32x4v h0 = *(const f32x4v*)(hpb + k0), h1 = *(const f32x4v*)(hpb + k0 + 4);
      const f32x4v g0 = *(const f32x4v*)(heb + k0), g1 = *(const f32x4v*)(heb + k0 + 4);
      const f32x4v p0 = *(const f32x4v*)(epb + k0), p1 = *(const f32x4v*)(epb + k0 + 4);
      const f32x4v q0 = *(const f32x4v*)(egb + k0), q1 = *(const f32x4v*)(egb + k0 + 4);
      const f32x4v x0 = h0 + g0, x1 = h1 + g1;
      const f32x4v d0 = p0 * q0 + 1.0f, d1 = p1 * q1 + 1.0f;
      f32x4v rc0, rc1;
      #pragma unroll
      for (int j = 0; j < 4; ++j) {
        rc0[j] = __builtin_amdgcn_rcpf(d0[j]);
        rc1[j] = __builtin_amdgcn_rcpf(d1[j]);
      }
      const f32x4v a0 = x0 * rc0, a1 = x1 * rc1;
      short8 bfrag;
      #pragma unroll
      for (int j = 0; j < 4; ++j) {
        bfrag[j]     = (short)bf16c(a0[j]);
        bfrag[4 + j] = (short)bf16c(a1[j]);
      }
      #pragma unroll
      for (int g = 0; g < 8; ++g)
        acc[g] = __builtin_amdgcn_mfma_f32_16x16x32_bf16(w2r[g][ks], bfrag, acc[g], 0, 0, 0);
    }

    // ---- WB: bias + silu -> bf16 H2 into private slab (swizzled) ----
    #pragma unroll
    for (int g = 0; g < 8; ++g) {
      const f32x4v bv = *(const f32x4v*)((const char*)ldsB2 + g * 64 + o * 16);
      const f32x4v y = acc[g] + bv;
      const f32x4v z = y * -1.44269504f;
      f32x4v d;
      #pragma unroll
      for (int j = 0; j < 4; ++j) d[j] = __builtin_amdgcn_exp2f(z[j]);
      d += 1.0f;
      f32x4v rc;
      #pragma unroll
      for (int j = 0; j < 4; ++j) rc[j] = __builtin_amdgcn_rcpf(d[j]);
      const f32x4v hh = y * rc;
      short4v pk;
      #pragma unroll
      for (int j = 0; j < 4; ++j) pk[j] = (short)bf16c(hh[j]);
      *(short4v*)(slab + ((r * 256 + g * 32 + o * 8) ^ rx)) = pk;
    }

    // ---- GEMM2: H2[r][k] from slab, W3 fragments from global (L1/L2-resident) ----
    f32x4v acc2 = {};
    #pragma unroll
    for (int ks2 = 0; ks2 < 4; ++ks2) {
      const short8 af  = *(const short8*)(slab + ((r * 256 + ks2 * 64 + o * 16) ^ rx));
      const short8 w3v = *(const short8*)(w3f + (ks2 * 64 + lane) * 8);
      acc2 = __builtin_amdgcn_mfma_f32_16x16x32_bf16(af, w3v, acc2, 0, 0, 0);
    }

    // ---- stores: row rr = o*4+q -> global row (b0 + rr>>3)*400 + e0 + (rr&7), col r ----
    #pragma unroll
    for (int q = 0; q < 4; ++q) {
      const int rr = o * 4 + q;
      const int gr = (b0 + (rr >> 3)) * 400 + e0 + (rr & 7);
      out[gr * 16 + r] = acc2[q] + b3v;
    }
  }
}

extern "C" void kernel_launch(void* const* d_in, const int* in_sizes, int n_in,
                              void* d_out, int out_size, void* d_ws, size_t ws_size,
                              hipStream_t stream) {
  const int*   z_j    = (const int*)d_in[0];
  const int*   z_k    = (const int*)d_in[1];
  const float* e_feat = (const float*)d_in[2];
  const float* z_emb  = (const float*)d_in[3];
  const float* W1     = (const float*)d_in[4];
  const float* b1     = (const float*)d_in[5];
  const float* W2     = (const float*)d_in[6];
  const float* b2     = (const float*)d_in[7];
  const float* W3     = (const float*)d_in[8];
  const float* b3     = (const float*)d_in[9];
  float* out = (float*)d_out;
  char*  ws  = (char*)d_ws;

  float*          hp   = (float*)(ws);                     // 1 MB @ 0x000000
  float*          he   = (float*)(ws + 0x100000);          // 200 KB
  float*          ehp  = (float*)(ws + 0x140000);          // 1 MB
  float*          ehe  = (float*)(ws + 0x240000);          // 200 KB
  unsigned short* w2f  = (unsigned short*)(ws + 0x280000); // 32 KB
  unsigned short* w3f  = (unsigned short*)(ws + 0x288000); // 4 KB

  hipLaunchKernelGGL(prep_emb, dim3(BPn + NEn), dim3(128), 0, stream,
                     z_j, z_k, e_feat, z_emb, W1, b1, hp, he, ehp, ehe);
  hipLaunchKernelGGL(prep_w, dim3(64), dim3(256), 0, stream, W2, W3, w2f, w3f);
  hipLaunchKernelGGL(fused_main, dim3(GRID), dim3(256), 0, stream,
                     hp, he, ehp, ehe, w2f, w3f, b2, b3, out);
}

// Round 10
// 84.752 us; speedup vs baseline: 1.9655x; 1.9655x over previous
//
#include <hip/hip_runtime.h>
#include <hip/hip_bf16.h>

// Problem constants
#define BPn   2048      // B*P
#define NEn   400
#define BT    4         // bp rows per tile
#define ET    8         // e rows per tile  -> 32-row tiles
#define NT    25600     // (2048/4)*(400/8)
#define GRID  1536      // 6 blocks/CU * 256 CU (2-wave blocks -> phase diversity)

typedef __attribute__((ext_vector_type(8)))  short  short8;
typedef __attribute__((ext_vector_type(4)))  short  short4v;
typedef __attribute__((ext_vector_type(16))) float  f32x16;
typedef __attribute__((ext_vector_type(4)))  float  f32x4v;

__device__ __forceinline__ unsigned short bf16c(float x) {
  return __builtin_bit_cast(unsigned short, __float2bfloat16(x));
}

// x * rcp(1+exp(-x)): avoids the IEEE div sequence (prep only).
__device__ __forceinline__ float silu_f(float x) {
  return x * __builtin_amdgcn_rcpf(1.0f + __expf(-x));
}

// async global->LDS, 16B per lane. LDS dest is wave-uniform base + lane*16.
__device__ __forceinline__ void glds16(const void* g, void* l) {
  __builtin_amdgcn_global_load_lds(
      (const __attribute__((address_space(1))) unsigned int*)g,
      (__attribute__((address_space(3))) unsigned int*)l, 16, 0, 0);
}

// ---------------- prep: hp[2048][128] and he[400][128] (f32) ----------------
__global__ void prep_emb(const int* __restrict__ z_j, const int* __restrict__ z_k,
                         const float* __restrict__ e_feat, const float* __restrict__ z_emb,
                         const float* __restrict__ W1, const float* __restrict__ b1,
                         float* __restrict__ hp, float* __restrict__ he)
{
  const int t = threadIdx.x;           // 0..127
  const int bidx = blockIdx.x;
  if (bidx < BPn) {
    const int zj = z_j[bidx], zk = z_k[bidx];
    const float* ej = z_emb + zj * 64;
    const float* ek = z_emb + zk * 64;
    float acc = b1[t];
    #pragma unroll 8
    for (int k = 0; k < 64; ++k) acc += ej[k] * W1[k * 128 + t];
    #pragma unroll 8
    for (int k = 0; k < 64; ++k) acc += ek[k] * W1[(64 + k) * 128 + t];
    hp[bidx * 128 + t] = acc;
  } else {
    const int e = bidx - BPn;          // 0..399
    float acc = 0.0f;
    #pragma unroll 8
    for (int k = 0; k < 32; ++k) acc += e_feat[e * 32 + k] * W1[(128 + k) * 128 + t];
    he[e * 128 + t] = acc;
  }
}

// ---------------- prep: weights to bf16 ----------------
// w2cm[n][k] = bf16(W2[k][n])  (col-major; read once per block into registers)
// w3f layout: [ks][lane][j] with B[k=ks*32+(lane>>4)*8+j][col=lane&15]
__global__ void prep_w(const float* __restrict__ W2, const float* __restrict__ W3,
                       unsigned short* __restrict__ w2cm, unsigned short* __restrict__ w3f)
{
  const int idx = blockIdx.x * 256 + threadIdx.x;
  if (idx < 16384) {
    const int n = idx >> 7, k = idx & 127;
    w2cm[idx] = bf16c(W2[k * 128 + n]);
  }
  if (idx < 2048) {
    const int ks = idx >> 9;
    const int l  = (idx >> 3) & 63;
    const int j  = idx & 7;
    const int k  = ks * 32 + ((l >> 4) & 3) * 8 + j;
    const int col = l & 15;
    w3f[idx] = bf16c(W3[k * 16 + col]);
  }
}

// ---------------- fused main: r7 structure + packed exp2 silu + setprio ----------------
// Phases: STAGE(t+1) -> GEMM1(t) -> siluWB(t)->ldsH -> bar2 -> GEMM2(t) + BUILD(t+1) -> stores(t) -> bar1
__global__ __launch_bounds__(128, 3)
void fused_main(const float* __restrict__ hp, const float* __restrict__ he,
                const unsigned short* __restrict__ w2cm, const unsigned short* __restrict__ w3f,
                const float* __restrict__ b2, const float* __restrict__ b3,
                float* __restrict__ out)
{
  __shared__ __align__(16) unsigned short ldsA[4096]; // 8KB: A = bf16(silu(hp+he)), 32 rows
  __shared__ __align__(16) unsigned short ldsH[4096]; // 8KB: H2, 32 rows
  __shared__ __align__(16) float          ldsS[1536]; // 6KB staging: [0,2KB) hp 4 rows, [2KB,6KB) he 8 rows
  __shared__ __align__(16) float          ldsB2[128]; // 512B: b2
  const int t    = threadIdx.x;       // 0..127
  const int lane = t & 63;
  const int wid  = t >> 6;            // 0..1; wave owns 64 output cols
  const int c  = lane & 31, hi = lane >> 5;

  // ---- per-block hoists (tile-independent) ----
  short8 w2r[2][8];
  #pragma unroll
  for (int n = 0; n < 2; ++n) {
    const unsigned short* p = w2cm + (wid * 64 + n * 32 + c) * 128 + hi * 8;
    #pragma unroll
    for (int ks = 0; ks < 8; ++ks)
      w2r[n][ks] = *(const short8*)(p + ks * 16);
  }
  short8 w3r[4];
  #pragma unroll
  for (int ks = 0; ks < 4; ++ks)
    w3r[ks] = *(const short8*)(w3f + (ks * 64 + lane) * 8);

  const int l16 = lane & 15, l4 = lane >> 4;
  const float b3v = b3[l16];
  ldsB2[t] = b2[t];

  // build-A per-thread constants: tile row = bp_local*8 + e_local
  const int row0 = t >> 4;              // 0..7  = e_local (fixed per thread)
  const int kb   = (t & 15) << 5;       // byte offset within a 512B f32 row
  const int k16  = (t & 15) << 4;       // byte offset within a 256B bf16 row

  // STAGE: 3 glds16 per wave. segs 0-1: hp rows b0..b0+3; segs 2-5: he rows e0..e0+7
  #define STAGE(b0_, e0_) do { \
    _Pragma("unroll") \
    for (int s_ = 0; s_ < 3; ++s_) { \
      const int seg_ = wid * 3 + s_; \
      const float* src_ = (seg_ < 2) ? (hp + (b0_) * 128 + seg_ * 256 + lane * 4) \
                                     : (he + (e0_) * 128 + (seg_ - 2) * 256 + lane * 4); \
      glds16(src_, (char*)ldsS + seg_ * 1024); \
    } \
  } while (0)

  // BUILD: ldsS -> silu (packed math, exp2) -> bf16 A tile in ldsA (swizzled)
  #define BUILD() do { \
    const char* Sb = (const char*)ldsS; \
    const f32x4v g0 = *(const f32x4v*)(Sb + 2048 + row0 * 512 + kb); \
    const f32x4v g1 = *(const f32x4v*)(Sb + 2048 + row0 * 512 + kb + 16); \
    _Pragma("unroll") \
    for (int i = 0; i < 4; ++i) { \
      const int row = i * 8 + row0; \
      const f32x4v h0 = *(const f32x4v*)(Sb + i * 512 + kb); \
      const f32x4v h1 = *(const f32x4v*)(Sb + i * 512 + kb + 16); \
      const f32x4v x0 = h0 + g0, x1 = h1 + g1; \
      const f32x4v z0 = x0 * -1.44269504f, z1 = x1 * -1.44269504f; \
      f32x4v d0, d1; \
      _Pragma("unroll") \
      for (int j = 0; j < 4; ++j) { d0[j] = __builtin_amdgcn_exp2f(z0[j]); d1[j] = __builtin_amdgcn_exp2f(z1[j]); } \
      d0 += 1.0f; d1 += 1.0f; \
      f32x4v r0_, r1_; \
      _Pragma("unroll") \
      for (int j = 0; j < 4; ++j) { r0_[j] = __builtin_amdgcn_rcpf(d0[j]); r1_[j] = __builtin_amdgcn_rcpf(d1[j]); } \
      const f32x4v a0 = x0 * r0_, a1 = x1 * r1_; \
      short8 av; \
      _Pragma("unroll") \
      for (int j = 0; j < 4; ++j) { av[j] = (short)bf16c(a0[j]); av[4 + j] = (short)bf16c(a1[j]); } \
      *(short8*)((char*)ldsA + ((row * 256 + k16) ^ ((row & 15) << 4))) = av; \
    } \
  } while (0)

  // ---- prologue: stage + build tile0 ----
  {
    const int tile0 = blockIdx.x;
    const int tbp = (int)(((unsigned)tile0 * 5243u) >> 18);  // tile/50 exact for tile<25600
    const int te  = tile0 - tbp * 50;
    STAGE(tbp * BT, te * ET);
  }
  __syncthreads();   // S(tile0) + ldsB2 visible
  BUILD();
  __syncthreads();   // bar#1: A(tile0) ready; ldsS free

  for (int tile = blockIdx.x; tile < NT; tile += GRID) {
    const int tbp = (int)(((unsigned)tile * 5243u) >> 18);
    const int te  = tile - tbp * 50;
    const int b0  = tbp * BT;
    const int e0  = te * ET;

    const int nxt = tile + GRID;
    const bool have_next = (nxt < NT);
    if (have_next) {
      const int ntbp = (int)(((unsigned)nxt * 5243u) >> 18);
      const int nte  = nxt - ntbp * 50;
      STAGE(ntbp * BT, nte * ET);   // in flight until bar2
    }

    // ---- GEMM1: acc[n] = H2pre^T fragments; B from registers ----
    f32x16 acc[2] = {};
    {
      const int swzA = (c & 15) << 4;
      __builtin_amdgcn_s_setprio(1);
      #pragma unroll
      for (int ks = 0; ks < 8; ++ks) {
        const int kb2 = (ks * 16 + hi * 8) * 2;
        short8 a0 = *(const short8*)((const char*)ldsA + ((c * 256 + kb2) ^ swzA));
        acc[0] = __builtin_amdgcn_mfma_f32_32x32x16_bf16(w2r[0][ks], a0, acc[0], 0, 0, 0);
        acc[1] = __builtin_amdgcn_mfma_f32_32x32x16_bf16(w2r[1][ks], a0, acc[1], 0, 0, 0);
      }
      __builtin_amdgcn_s_setprio(0);
    }

    // ---- bias + silu -> H2 bf16 into ldsH; lane owns row c. Packed exp2 math. ----
    {
      const int swzH = (c & 15) << 4;
      char* rbase = (char*)ldsH + c * 256;
      #pragma unroll
      for (int n = 0; n < 2; ++n) {
        #pragma unroll
        for (int q = 0; q < 4; ++q) {
          const int colb = wid * 64 + n * 32 + q * 8 + hi * 4;
          const f32x4v bq = *(const f32x4v*)(ldsB2 + colb);
          f32x4v y = { acc[n][q * 4 + 0], acc[n][q * 4 + 1], acc[n][q * 4 + 2], acc[n][q * 4 + 3] };
          y += bq;
          const f32x4v z = y * -1.44269504f;
          f32x4v d;
          #pragma unroll
          for (int j = 0; j < 4; ++j) d[j] = __builtin_amdgcn_exp2f(z[j]);
          d += 1.0f;
          f32x4v rc;
          #pragma unroll
          for (int j = 0; j < 4; ++j) rc[j] = __builtin_amdgcn_rcpf(d[j]);
          rc *= y;
          short4v pk;
          #pragma unroll
          for (int j = 0; j < 4; ++j) pk[j] = (short)bf16c(rc[j]);
          *(short4v*)(rbase + ((colb * 2) ^ swzH)) = pk;
        }
      }
    }
    __syncthreads();   // bar#2: H2 ready; S(t+1) visible; ldsA free

    // ---- GEMM2: H2 (32x128) @ W3 (128x16) ----
    f32x4v acc2 = {};
    {
      const int row2 = wid * 16 + l16;
      const int swz2 = l16 << 4;
      __builtin_amdgcn_s_setprio(1);
      #pragma unroll
      for (int ks = 0; ks < 4; ++ks) {
        const int kb2 = ks * 64 + l4 * 16;
        short8 af = *(const short8*)((const char*)ldsH + ((row2 * 256 + kb2) ^ swz2));
        acc2 = __builtin_amdgcn_mfma_f32_16x16x32_bf16(af, w3r[ks], acc2, 0, 0, 0);
      }
      __builtin_amdgcn_s_setprio(0);
    }

    // ---- build A(t+1) from staged S(t+1) (overlaps GEMM2 latency) ----
    if (have_next) BUILD();

    // ---- store: tile row r -> global row (b0 + r>>3)*400 + (e0 + r&7) ----
    {
      const int obase = (b0 * 400 + e0);
      #pragma unroll
      for (int j = 0; j < 4; ++j) {
        const int r   = wid * 16 + l4 * 4 + j;
        const int rg  = obase + (r >> 3) * 400 + (r & 7);
        out[rg * 16 + l16] = acc2[j] + b3v;
      }
    }
    __syncthreads();   // bar#1: A(t+1) ready; ldsS free; ldsH free
  }
  #undef STAGE
  #undef BUILD
}

extern "C" void kernel_launch(void* const* d_in, const int* in_sizes, int n_in,
                              void* d_out, int out_size, void* d_ws, size_t ws_size,
                              hipStream_t stream) {
  const int*   z_j    = (const int*)d_in[0];
  const int*   z_k    = (const int*)d_in[1];
  const float* e_feat = (const float*)d_in[2];
  const float* z_emb  = (const float*)d_in[3];
  const float* W1     = (const float*)d_in[4];
  const float* b1     = (const float*)d_in[5];
  const float* W2     = (const float*)d_in[6];
  const float* b2     = (const float*)d_in[7];
  const float* W3     = (const float*)d_in[8];
  const float* b3     = (const float*)d_in[9];
  float* out = (float*)d_out;
  char*  ws  = (char*)d_ws;

  float*          hp   = (float*)(ws);                     // 2048*128*4 = 1 MB
  float*          he   = (float*)(ws + (1 << 20));         // 400*128*4  = 200 KB
  unsigned short* w2cm = (unsigned short*)(ws + 0x140000); // 32 KB
  unsigned short* w3f  = (unsigned short*)(ws + 0x148000); // 4 KB

  hipLaunchKernelGGL(prep_emb, dim3(BPn + NEn), dim3(128), 0, stream,
                     z_j, z_k, e_feat, z_emb, W1, b1, hp, he);
  hipLaunchKernelGGL(prep_w, dim3(64), dim3(256), 0, stream, W2, W3, w2cm, w3f);
  hipLaunchKernelGGL(fused_main, dim3(GRID), dim3(128), 0, stream,
                     hp, he, w2cm, w3f, b2, b3, out);
}